// Round 1
// baseline (4537.671 us; speedup 1.0000x reference)
//
#include <hip/hip_runtime.h>
#include <math.h>

static constexpr int H = 480, W = 320, NH = 24, NW = 16, NB = 384;
static constexpr int HW = H * W;            // 153600
static constexpr int H2 = 240, W2 = 160;
static constexpr int HW2 = H2 * W2;         // 38400
static constexpr int H4 = 120, W4 = 80;
static constexpr int HW4 = H4 * W4;         // 9600
static constexpr int IMG_PIX = 3 * 1920 * 1280;  // 7372800

__device__ __forceinline__ int iclamp(int v, int lo, int hi) {
    return v < lo ? lo : (v > hi ? hi : v);
}

// ---------------- classifier ----------------

// conv 3->32, 3x3, edge pad, relu.  thread per pixel, all 32 couts.
__global__ __launch_bounds__(256) void k_cls1(const float* __restrict__ x,
                                              const float* __restrict__ w,
                                              const float* __restrict__ b,
                                              float* __restrict__ out) {
    int p = blockIdx.x * 256 + threadIdx.x;
    if (p >= HW) return;
    int y = p / W, xx = p - y * W;
    float in[3][9];
#pragma unroll
    for (int ci = 0; ci < 3; ++ci)
#pragma unroll
        for (int dy = 0; dy < 3; ++dy) {
            int yy = iclamp(y + dy - 1, 0, H - 1);
#pragma unroll
            for (int dx = 0; dx < 3; ++dx) {
                int xc = iclamp(xx + dx - 1, 0, W - 1);
                in[ci][dy * 3 + dx] = x[ci * HW + yy * W + xc];
            }
        }
#pragma unroll
    for (int co = 0; co < 32; ++co) {
        float acc = b[co];
#pragma unroll
        for (int k = 0; k < 27; ++k) acc = fmaf(w[co * 27 + k], in[k / 9][k % 9], acc);
        out[co * HW + p] = fmaxf(acc, 0.f);
    }
}

// conv 32->32 edge pad + relu + 2x2 maxpool. thread per pooled pixel, 8 couts per wg (blockIdx.y).
__global__ __launch_bounds__(256) void k_cls2(const float* __restrict__ in,
                                              const float* __restrict__ w,
                                              const float* __restrict__ b,
                                              float* __restrict__ out) {
    int p = blockIdx.x * 256 + threadIdx.x;  // 38400 pooled pixels
    if (p >= HW2) return;
    int py = p / W2, px = p - py * W2;
    int coc = blockIdx.y;  // 0..3
    float acc[8][4];
#pragma unroll
    for (int co = 0; co < 8; ++co) {
        float bb = b[coc * 8 + co];
        acc[co][0] = bb; acc[co][1] = bb; acc[co][2] = bb; acc[co][3] = bb;
    }
    for (int ci = 0; ci < 32; ++ci) {
        float v[4][4];
#pragma unroll
        for (int i = 0; i < 4; ++i) {
            int yr = iclamp(2 * py - 1 + i, 0, H - 1);
#pragma unroll
            for (int j = 0; j < 4; ++j) {
                int xc = iclamp(2 * px - 1 + j, 0, W - 1);
                v[i][j] = in[ci * HW + yr * W + xc];
            }
        }
#pragma unroll
        for (int co = 0; co < 8; ++co) {
            const float* wp = w + (coc * 8 + co) * 288 + ci * 9;
#pragma unroll
            for (int dy = 0; dy < 3; ++dy)
#pragma unroll
                for (int dx = 0; dx < 3; ++dx) {
                    float ww = wp[dy * 3 + dx];
                    acc[co][0] = fmaf(ww, v[dy][dx], acc[co][0]);
                    acc[co][1] = fmaf(ww, v[dy][dx + 1], acc[co][1]);
                    acc[co][2] = fmaf(ww, v[dy + 1][dx], acc[co][2]);
                    acc[co][3] = fmaf(ww, v[dy + 1][dx + 1], acc[co][3]);
                }
        }
    }
#pragma unroll
    for (int co = 0; co < 8; ++co) {
        float m = fmaxf(fmaxf(acc[co][0], acc[co][1]), fmaxf(acc[co][2], acc[co][3]));
        out[(coc * 8 + co) * HW2 + p] = fmaxf(m, 0.f);
    }
}

// conv 32->16 edge pad relu at 240x160. thread per pixel, 16 couts.
__global__ __launch_bounds__(256) void k_cls3(const float* __restrict__ in,
                                              const float* __restrict__ w,
                                              const float* __restrict__ b,
                                              float* __restrict__ out) {
    int p = blockIdx.x * 256 + threadIdx.x;
    if (p >= HW2) return;
    int y = p / W2, xx = p - y * W2;
    float acc[16];
#pragma unroll
    for (int co = 0; co < 16; ++co) acc[co] = b[co];
    for (int ci = 0; ci < 32; ++ci) {
        float v[9];
#pragma unroll
        for (int dy = 0; dy < 3; ++dy) {
            int yy = iclamp(y + dy - 1, 0, H2 - 1);
#pragma unroll
            for (int dx = 0; dx < 3; ++dx) {
                int xc = iclamp(xx + dx - 1, 0, W2 - 1);
                v[dy * 3 + dx] = in[ci * HW2 + yy * W2 + xc];
            }
        }
#pragma unroll
        for (int co = 0; co < 16; ++co)
#pragma unroll
            for (int t = 0; t < 9; ++t)
                acc[co] = fmaf(w[co * 288 + ci * 9 + t], v[t], acc[co]);
    }
#pragma unroll
    for (int co = 0; co < 16; ++co) out[co * HW2 + p] = fmaxf(acc[co], 0.f);
}

// conv 16->8 edge pad + relu + pool at 240x160 -> (8,120,80)
__global__ __launch_bounds__(256) void k_cls4(const float* __restrict__ in,
                                              const float* __restrict__ w,
                                              const float* __restrict__ b,
                                              float* __restrict__ out) {
    int p = blockIdx.x * 256 + threadIdx.x;
    if (p >= HW4) return;
    int py = p / W4, px = p - py * W4;
    float acc[8][4];
#pragma unroll
    for (int co = 0; co < 8; ++co) {
        float bb = b[co];
        acc[co][0] = bb; acc[co][1] = bb; acc[co][2] = bb; acc[co][3] = bb;
    }
    for (int ci = 0; ci < 16; ++ci) {
        float v[4][4];
#pragma unroll
        for (int i = 0; i < 4; ++i) {
            int yr = iclamp(2 * py - 1 + i, 0, H2 - 1);
#pragma unroll
            for (int j = 0; j < 4; ++j) {
                int xc = iclamp(2 * px - 1 + j, 0, W2 - 1);
                v[i][j] = in[ci * HW2 + yr * W2 + xc];
            }
        }
#pragma unroll
        for (int co = 0; co < 8; ++co) {
            const float* wp = w + co * 144 + ci * 9;
#pragma unroll
            for (int dy = 0; dy < 3; ++dy)
#pragma unroll
                for (int dx = 0; dx < 3; ++dx) {
                    float ww = wp[dy * 3 + dx];
                    acc[co][0] = fmaf(ww, v[dy][dx], acc[co][0]);
                    acc[co][1] = fmaf(ww, v[dy][dx + 1], acc[co][1]);
                    acc[co][2] = fmaf(ww, v[dy + 1][dx], acc[co][2]);
                    acc[co][3] = fmaf(ww, v[dy + 1][dx + 1], acc[co][3]);
                }
        }
    }
#pragma unroll
    for (int co = 0; co < 8; ++co) {
        float m = fmaxf(fmaxf(acc[co][0], acc[co][1]), fmaxf(acc[co][2], acc[co][3]));
        out[co * HW4 + p] = fmaxf(m, 0.f);
    }
}

// conv 8->1, 5x5, stride 5, no pad, on (8,120,80) -> (24,16); sigmoid; write class vector
__global__ __launch_bounds__(384) void k_cls5(const float* __restrict__ in,
                                              const float* __restrict__ w,
                                              const float* __restrict__ b,
                                              float* __restrict__ clsv,
                                              float* __restrict__ out_cls) {
    int tid = threadIdx.x;
    if (tid >= NB) return;
    int oy = tid / NW, ox = tid - oy * NW;
    float s = b[0];
    for (int ci = 0; ci < 8; ++ci)
#pragma unroll
        for (int ky = 0; ky < 5; ++ky)
#pragma unroll
            for (int kx = 0; kx < 5; ++kx)
                s = fmaf(w[ci * 25 + ky * 5 + kx],
                         in[ci * HW4 + (oy * 5 + ky) * W4 + (ox * 5 + kx)], s);
    float sig = 1.f / (1.f + expf(-s));
    clsv[tid] = sig;
    out_cls[tid] = sig;
}

// ---------------- block branches ----------------

// first conv of each branch (3->64 complex, 3->16 light), zero-pad block conv.
// one workgroup (1024 threads = 1/pixel) per block.
__global__ __launch_bounds__(1024) void k_first(const float* __restrict__ x,
                                                const float* __restrict__ wl,
                                                const float* __restrict__ bl,
                                                const float* __restrict__ wc,
                                                const float* __restrict__ bc,
                                                const float* __restrict__ clsv,
                                                int b0, float* __restrict__ t1) {
    int bL = blockIdx.x;
    int b = b0 + bL;
    bool cx = clsv[b] > 0.5f;
    int bh = b / NW, bw = b - bh * NW;
    __shared__ float lds[3 * 34 * 34];
    int tid = threadIdx.x;
    for (int i = tid; i < 3 * 1156; i += 1024) {
        int ci = i / 1156, rem = i - ci * 1156;
        int ry = rem / 34, rx = rem - ry * 34;
        int ly = ry - 1, lx = rx - 1;                 // block-local coords, conv zero-pad
        int yg = bh * 20 + ly - 6, xg = bw * 20 + lx - 6;  // global coords (xp zero-pad)
        float v = 0.f;
        if ((unsigned)ly < 32u && (unsigned)lx < 32u &&
            (unsigned)yg < (unsigned)H && (unsigned)xg < (unsigned)W)
            v = x[ci * HW + yg * W + xg];
        lds[i] = v;
    }
    __syncthreads();
    int py = tid >> 5, px = tid & 31;
    float in[27];
#pragma unroll
    for (int ci = 0; ci < 3; ++ci)
#pragma unroll
        for (int dy = 0; dy < 3; ++dy)
#pragma unroll
            for (int dx = 0; dx < 3; ++dx)
                in[ci * 9 + dy * 3 + dx] = lds[ci * 1156 + (py + dy) * 34 + (px + dx)];
    float* outp = t1 + (long)bL * 65536 + tid;
    if (cx) {
#pragma unroll
        for (int co = 0; co < 64; ++co) {
            float acc = bc[co];
#pragma unroll
            for (int k = 0; k < 27; ++k) acc = fmaf(wc[co * 27 + k], in[k], acc);
            outp[co * 1024] = fmaxf(acc, 0.f);
        }
    } else {
#pragma unroll
        for (int co = 0; co < 16; ++co) {
            float acc = bl[co];
#pragma unroll
            for (int k = 0; k < 27; ++k) acc = fmaf(wl[co * 27 + k], in[k], acc);
            outp[co * 1024] = fmaxf(acc, 0.f);
        }
    }
}

// generic 3x3 zero-pad conv on 32x32 blocks, CIN -> COUT, one wg per block,
// early-exit unless the block's branch matches WANTC. LDS-staged in 8-ch chunks.
template <int CIN, int COUT, bool RELU, bool WANTC>
__global__ __launch_bounds__(1024) void k_conv(const float* __restrict__ in, int in_stride,
                                               const float* __restrict__ w,
                                               const float* __restrict__ bias,
                                               const float* __restrict__ clsv, int b0,
                                               float* __restrict__ out, int out_stride) {
    int bL = blockIdx.x;
    int b = b0 + bL;
    if ((clsv[b] > 0.5f) != WANTC) return;
    constexpr int CPB = 8;
    extern __shared__ float lds[];  // CPB*34*34 floats
    int tid = threadIdx.x;
    int py = tid >> 5, px = tid & 31;
    float acc[COUT];
#pragma unroll
    for (int co = 0; co < COUT; ++co) acc[co] = bias[co];
    const float* inb = in + (long)bL * in_stride;
    for (int cb = 0; cb < CIN; cb += CPB) {
        __syncthreads();
        for (int i = tid; i < CPB * 1156; i += 1024) {
            int ci = i / 1156, rem = i - ci * 1156;
            int ry = rem / 34, rx = rem - ry * 34;
            int ly = ry - 1, lx = rx - 1;
            float v = 0.f;
            if ((unsigned)ly < 32u && (unsigned)lx < 32u)
                v = inb[(cb + ci) * 1024 + ly * 32 + lx];
            lds[i] = v;
        }
        __syncthreads();
#pragma unroll 2
        for (int ci = 0; ci < CPB; ++ci) {
            float v[9];
#pragma unroll
            for (int dy = 0; dy < 3; ++dy)
#pragma unroll
                for (int dx = 0; dx < 3; ++dx)
                    v[dy * 3 + dx] = lds[ci * 1156 + (py + dy) * 34 + (px + dx)];
            const float* wp = w + (cb + ci) * 9;
#pragma unroll
            for (int co = 0; co < COUT; ++co)
#pragma unroll
                for (int t = 0; t < 9; ++t)
                    acc[co] = fmaf(wp[co * CIN * 9 + t], v[t], acc[co]);
        }
    }
    float* op = out + (long)bL * out_stride + tid;
#pragma unroll
    for (int co = 0; co < COUT; ++co) {
        float r = acc[co];
        if (RELU) r = fmaxf(r, 0.f);
        op[co * 1024] = r;
    }
}

// pixel shuffle + clip + crop + reassemble. thread per output pixel of the chunk.
__global__ __launch_bounds__(256) void k_assemble(const float* __restrict__ t3, int b0, int nb,
                                                  float* __restrict__ out) {
    int idx = blockIdx.x * 256 + threadIdx.x;
    if (idx >= nb * 19200) return;
    int bL = idx / 19200;
    int rem = idx - bL * 19200;
    int ch = rem / 6400;
    int rem2 = rem - ch * 6400;
    int r = rem2 / 80, s = rem2 - r * 80;
    int b = b0 + bL;
    int bh = b / NW, bw = b - bh * NW;
    int yy = r + 24, xx = s + 24;
    int pc = ch * 16 + (yy & 3) * 4 + (xx & 3);
    float v = t3[(long)bL * 49152 + pc * 1024 + (yy >> 2) * 32 + (xx >> 2)];
    v = fminf(fmaxf(v, 0.f), 1.f);
    out[ch * (1920 * 1280) + (bh * 80 + r) * 1280 + (bw * 80 + s)] = v;
}

extern "C" void kernel_launch(void* const* d_in, const int* in_sizes, int n_in,
                              void* d_out, int out_size, void* d_ws, size_t ws_size,
                              hipStream_t stream) {
    const float* x      = (const float*)d_in[0];
    const float* cls_w1 = (const float*)d_in[1];
    const float* cls_b1 = (const float*)d_in[2];
    const float* cls_w2 = (const float*)d_in[3];
    const float* cls_b2 = (const float*)d_in[4];
    const float* cls_w3 = (const float*)d_in[5];
    const float* cls_b3 = (const float*)d_in[6];
    const float* cls_w4 = (const float*)d_in[7];
    const float* cls_b4 = (const float*)d_in[8];
    const float* cls_w5 = (const float*)d_in[9];
    const float* cls_b5 = (const float*)d_in[10];
    const float* lt_w1  = (const float*)d_in[11];
    const float* lt_b1  = (const float*)d_in[12];
    const float* lt_w2  = (const float*)d_in[13];
    const float* lt_b2  = (const float*)d_in[14];
    const float* cx_w1  = (const float*)d_in[15];
    const float* cx_b1  = (const float*)d_in[16];
    const float* cx_w2  = (const float*)d_in[17];
    const float* cx_b2  = (const float*)d_in[18];
    const float* cx_w3  = (const float*)d_in[19];
    const float* cx_b3  = (const float*)d_in[20];

    float* ws = (float*)d_ws;
    float* out = (float*)d_out;

    size_t off = 0;
    float* c1 = ws + off;  off += (size_t)32 * HW;    // 4,915,200
    float* c2 = ws + off;  off += (size_t)32 * HW2;   // 1,228,800
    float* c3 = ws + off;  off += (size_t)16 * HW2;   //   614,400
    float* c4 = ws + off;  off += (size_t)8 * HW4;    //    76,800
    float* clsv = ws + off; off += 384;
    size_t fixed = off;

    // per-block temporaries: t1 (64ch), t2 (64ch), t3 (48ch), chunked over blocks.
    long avail = (long)(ws_size / 4) - (long)fixed;
    long per_block = 65536 + 65536 + 49152;  // 180224 floats
    long cmax = avail / per_block;
    int chunk = (int)(cmax < 1 ? 1 : (cmax > NB ? NB : cmax));
    float* t1 = ws + fixed;
    float* t2 = t1 + (long)chunk * 65536;
    float* t3 = t2 + (long)chunk * 65536;

    k_cls1<<<(HW + 255) / 256, 256, 0, stream>>>(x, cls_w1, cls_b1, c1);
    k_cls2<<<dim3((HW2 + 255) / 256, 4), 256, 0, stream>>>(c1, cls_w2, cls_b2, c2);
    k_cls3<<<(HW2 + 255) / 256, 256, 0, stream>>>(c2, cls_w3, cls_b3, c3);
    k_cls4<<<(HW4 + 255) / 256, 256, 0, stream>>>(c3, cls_w4, cls_b4, c4);
    k_cls5<<<1, 384, 0, stream>>>(c4, cls_w5, cls_b5, clsv, out + IMG_PIX);

    const int ldsb = 8 * 1156 * 4;  // 36992 B
    for (int b0 = 0; b0 < NB; b0 += chunk) {
        int n = chunk < (NB - b0) ? chunk : (NB - b0);
        k_first<<<n, 1024, 0, stream>>>(x, lt_w1, lt_b1, cx_w1, cx_b1, clsv, b0, t1);
        k_conv<64, 64, true, true><<<n, 1024, ldsb, stream>>>(t1, 65536, cx_w2, cx_b2, clsv, b0, t2, 65536);
        k_conv<64, 48, false, true><<<n, 1024, ldsb, stream>>>(t2, 65536, cx_w3, cx_b3, clsv, b0, t3, 49152);
        k_conv<16, 48, false, false><<<n, 1024, ldsb, stream>>>(t1, 65536, lt_w2, lt_b2, clsv, b0, t3, 49152);
        k_assemble<<<(n * 19200 + 255) / 256, 256, 0, stream>>>(t3, b0, n, out);
    }
}

// Round 2
// 441.560 us; speedup vs baseline: 10.2764x; 10.2764x over previous
//
#include <hip/hip_runtime.h>
#include <hip/hip_bf16.h>
#include <math.h>

static constexpr int H = 480, W = 320, NH = 24, NW = 16, NB = 384;
static constexpr int HW = H * W;            // 153600
static constexpr int H2 = 240, W2 = 160;
static constexpr int HW2 = H2 * W2;         // 38400
static constexpr int H4 = 120, W4 = 80;
static constexpr int HW4 = H4 * W4;         // 9600
static constexpr int IMG_PIX = 3 * 1920 * 1280;  // 7372800

typedef __attribute__((ext_vector_type(8))) short short8;
typedef __attribute__((ext_vector_type(4))) float f32x4;
typedef __attribute__((ext_vector_type(8))) unsigned short ushort8;

__device__ __forceinline__ int iclamp(int v, int lo, int hi) {
    return v < lo ? lo : (v > hi ? hi : v);
}
__device__ __forceinline__ short f2bf(float x) {
    __hip_bfloat16 h = __float2bfloat16(x);
    return *reinterpret_cast<short*>(&h);
}
__device__ __forceinline__ float bf2f(unsigned short u) {
    __hip_bfloat16 h = *reinterpret_cast<__hip_bfloat16*>(&u);
    return __bfloat162float(h);
}

// ---------------- classifier (fp32, unchanged semantics) ----------------

__global__ __launch_bounds__(256) void k_cls1(const float* __restrict__ x,
                                              const float* __restrict__ w,
                                              const float* __restrict__ b,
                                              float* __restrict__ out) {
    int p = blockIdx.x * 256 + threadIdx.x;
    if (p >= HW) return;
    int y = p / W, xx = p - y * W;
    float in[3][9];
#pragma unroll
    for (int ci = 0; ci < 3; ++ci)
#pragma unroll
        for (int dy = 0; dy < 3; ++dy) {
            int yy = iclamp(y + dy - 1, 0, H - 1);
#pragma unroll
            for (int dx = 0; dx < 3; ++dx) {
                int xc = iclamp(xx + dx - 1, 0, W - 1);
                in[ci][dy * 3 + dx] = x[ci * HW + yy * W + xc];
            }
        }
#pragma unroll
    for (int co = 0; co < 32; ++co) {
        float acc = b[co];
#pragma unroll
        for (int k = 0; k < 27; ++k) acc = fmaf(w[co * 27 + k], in[k / 9][k % 9], acc);
        out[co * HW + p] = fmaxf(acc, 0.f);
    }
}

__global__ __launch_bounds__(256) void k_cls2(const float* __restrict__ in,
                                              const float* __restrict__ w,
                                              const float* __restrict__ b,
                                              float* __restrict__ out) {
    int p = blockIdx.x * 256 + threadIdx.x;
    if (p >= HW2) return;
    int py = p / W2, px = p - py * W2;
    int coc = blockIdx.y;
    float acc[8][4];
#pragma unroll
    for (int co = 0; co < 8; ++co) {
        float bb = b[coc * 8 + co];
        acc[co][0] = bb; acc[co][1] = bb; acc[co][2] = bb; acc[co][3] = bb;
    }
    for (int ci = 0; ci < 32; ++ci) {
        float v[4][4];
#pragma unroll
        for (int i = 0; i < 4; ++i) {
            int yr = iclamp(2 * py - 1 + i, 0, H - 1);
#pragma unroll
            for (int j = 0; j < 4; ++j) {
                int xc = iclamp(2 * px - 1 + j, 0, W - 1);
                v[i][j] = in[ci * HW + yr * W + xc];
            }
        }
#pragma unroll
        for (int co = 0; co < 8; ++co) {
            const float* wp = w + (coc * 8 + co) * 288 + ci * 9;
#pragma unroll
            for (int dy = 0; dy < 3; ++dy)
#pragma unroll
                for (int dx = 0; dx < 3; ++dx) {
                    float ww = wp[dy * 3 + dx];
                    acc[co][0] = fmaf(ww, v[dy][dx], acc[co][0]);
                    acc[co][1] = fmaf(ww, v[dy][dx + 1], acc[co][1]);
                    acc[co][2] = fmaf(ww, v[dy + 1][dx], acc[co][2]);
                    acc[co][3] = fmaf(ww, v[dy + 1][dx + 1], acc[co][3]);
                }
        }
    }
#pragma unroll
    for (int co = 0; co < 8; ++co) {
        float m = fmaxf(fmaxf(acc[co][0], acc[co][1]), fmaxf(acc[co][2], acc[co][3]));
        out[(coc * 8 + co) * HW2 + p] = fmaxf(m, 0.f);
    }
}

__global__ __launch_bounds__(256) void k_cls3(const float* __restrict__ in,
                                              const float* __restrict__ w,
                                              const float* __restrict__ b,
                                              float* __restrict__ out) {
    int p = blockIdx.x * 256 + threadIdx.x;
    if (p >= HW2) return;
    int y = p / W2, xx = p - y * W2;
    float acc[16];
#pragma unroll
    for (int co = 0; co < 16; ++co) acc[co] = b[co];
    for (int ci = 0; ci < 32; ++ci) {
        float v[9];
#pragma unroll
        for (int dy = 0; dy < 3; ++dy) {
            int yy = iclamp(y + dy - 1, 0, H2 - 1);
#pragma unroll
            for (int dx = 0; dx < 3; ++dx) {
                int xc = iclamp(xx + dx - 1, 0, W2 - 1);
                v[dy * 3 + dx] = in[ci * HW2 + yy * W2 + xc];
            }
        }
#pragma unroll
        for (int co = 0; co < 16; ++co)
#pragma unroll
            for (int t = 0; t < 9; ++t)
                acc[co] = fmaf(w[co * 288 + ci * 9 + t], v[t], acc[co]);
    }
#pragma unroll
    for (int co = 0; co < 16; ++co) out[co * HW2 + p] = fmaxf(acc[co], 0.f);
}

__global__ __launch_bounds__(256) void k_cls4(const float* __restrict__ in,
                                              const float* __restrict__ w,
                                              const float* __restrict__ b,
                                              float* __restrict__ out) {
    int p = blockIdx.x * 256 + threadIdx.x;
    if (p >= HW4) return;
    int py = p / W4, px = p - py * W4;
    float acc[8][4];
#pragma unroll
    for (int co = 0; co < 8; ++co) {
        float bb = b[co];
        acc[co][0] = bb; acc[co][1] = bb; acc[co][2] = bb; acc[co][3] = bb;
    }
    for (int ci = 0; ci < 16; ++ci) {
        float v[4][4];
#pragma unroll
        for (int i = 0; i < 4; ++i) {
            int yr = iclamp(2 * py - 1 + i, 0, H2 - 1);
#pragma unroll
            for (int j = 0; j < 4; ++j) {
                int xc = iclamp(2 * px - 1 + j, 0, W2 - 1);
                v[i][j] = in[ci * HW2 + yr * W2 + xc];
            }
        }
#pragma unroll
        for (int co = 0; co < 8; ++co) {
            const float* wp = w + co * 144 + ci * 9;
#pragma unroll
            for (int dy = 0; dy < 3; ++dy)
#pragma unroll
                for (int dx = 0; dx < 3; ++dx) {
                    float ww = wp[dy * 3 + dx];
                    acc[co][0] = fmaf(ww, v[dy][dx], acc[co][0]);
                    acc[co][1] = fmaf(ww, v[dy][dx + 1], acc[co][1]);
                    acc[co][2] = fmaf(ww, v[dy + 1][dx], acc[co][2]);
                    acc[co][3] = fmaf(ww, v[dy + 1][dx + 1], acc[co][3]);
                }
        }
    }
#pragma unroll
    for (int co = 0; co < 8; ++co) {
        float m = fmaxf(fmaxf(acc[co][0], acc[co][1]), fmaxf(acc[co][2], acc[co][3]));
        out[co * HW4 + p] = fmaxf(m, 0.f);
    }
}

__global__ __launch_bounds__(384) void k_cls5(const float* __restrict__ in,
                                              const float* __restrict__ w,
                                              const float* __restrict__ b,
                                              float* __restrict__ clsv,
                                              float* __restrict__ out_cls) {
    int tid = threadIdx.x;
    if (tid >= NB) return;
    int oy = tid / NW, ox = tid - oy * NW;
    float s = b[0];
    for (int ci = 0; ci < 8; ++ci)
#pragma unroll
        for (int ky = 0; ky < 5; ++ky)
#pragma unroll
            for (int kx = 0; kx < 5; ++kx)
                s = fmaf(w[ci * 25 + ky * 5 + kx],
                         in[ci * HW4 + (oy * 5 + ky) * W4 + (ox * 5 + kx)], s);
    float sig = 1.f / (1.f + expf(-s));
    clsv[tid] = sig;
    out_cls[tid] = sig;
}

// ---------------- block branches: bf16 MFMA ----------------

// first conv of both branches via im2col + MFMA. grid = n blocks, 512 threads.
// dyn LDS: A im2col [1024][40] shorts + halo 3*34*34 shorts = 88,856 B
__global__ __launch_bounds__(512, 2) void k_first(const float* __restrict__ x,
                                                  const float* __restrict__ wl,
                                                  const float* __restrict__ bl,
                                                  const float* __restrict__ wc,
                                                  const float* __restrict__ bc,
                                                  const float* __restrict__ clsv,
                                                  int b0, __hip_bfloat16* __restrict__ t1) {
    extern __shared__ unsigned short sh[];
    unsigned short* A = sh;                 // 1024*40
    unsigned short* halo = sh + 1024 * 40;  // 3*1156
    int bL = blockIdx.x, b = b0 + bL;
    bool cx = clsv[b] > 0.5f;
    int bh = b / NW, bw = b - bh * NW;
    int tid = threadIdx.x;
    for (int i = tid; i < 3 * 1156; i += 512) {
        int ci = i / 1156, rem = i - ci * 1156;
        int ry = rem / 34, rx = rem - ry * 34;
        int yg = bh * 20 + ry - 7, xg = bw * 20 + rx - 7;
        float v = ((unsigned)yg < (unsigned)H && (unsigned)xg < (unsigned)W)
                      ? x[ci * HW + yg * W + xg] : 0.f;
        halo[i] = (unsigned short)f2bf(v);
    }
    __syncthreads();
    for (int v = tid; v < 1024 * 32; v += 512) {
        int p = v >> 5, k = v & 31;
        unsigned short val = 0;
        if (k < 27) {
            int ci = k / 9, t = k - ci * 9;
            int dy = t / 3, dx = t - dy * 3;
            int y = p >> 5, xx = p & 31;
            val = halo[ci * 1156 + (y + dy) * 34 + (xx + dx)];
        }
        A[p * 40 + k] = val;
    }
    __syncthreads();
    int lane = tid & 63, wave = tid >> 6;
    int col = lane & 15, kq = lane >> 4;
    const float* w = cx ? wc : wl;
    const float* bi = cx ? bc : bl;
    int nT = cx ? 4 : 1;
    __hip_bfloat16* outb = t1 + (long)bL * 65536;
    for (int nt = 0; nt < nT; ++nt) {
        int co = nt * 16 + col;
        short8 Bf;
#pragma unroll
        for (int j = 0; j < 8; ++j) {
            int k = kq * 8 + j;
            Bf[j] = (k < 27) ? f2bf(w[co * 27 + k]) : (short)0;
        }
        float bv = bi[co];
#pragma unroll 1
        for (int i = 0; i < 8; ++i) {
            int mt = wave * 8 + i;
            short8 a = *(const short8*)(A + (mt * 16 + col) * 40 + kq * 8);
            f32x4 acc = {bv, bv, bv, bv};
            acc = __builtin_amdgcn_mfma_f32_16x16x32_bf16(a, Bf, acc, 0, 0, 0);
            int prow = mt * 16 + kq * 4;
#pragma unroll
            for (int r = 0; r < 4; ++r)
                outb[(prow + r) * 64 + co] = __float2bfloat16(fmaxf(acc[r], 0.f));
        }
    }
}

// one pass over NT2 n-tiles (<=2). B frags in registers; A streamed from LDS.
template <int NT2, int KC, int CIN, int CS, int GOUT, bool RELU>
__device__ __forceinline__ void bconv_pass(const unsigned short* __restrict__ lds,
                                           const float* __restrict__ w,
                                           const float* __restrict__ bias,
                                           int ntbase, int tid,
                                           __hip_bfloat16* __restrict__ outb) {
    int lane = tid & 63, wave = tid >> 6;
    int col = lane & 15, kq = lane >> 4;
    short8 B[NT2][KC][9];
    float bv[NT2];
#pragma unroll
    for (int nt = 0; nt < NT2; ++nt) {
        int co = (ntbase + nt) * 16 + col;
        bv[nt] = bias[co];
#pragma unroll
        for (int kc = 0; kc < KC; ++kc)
#pragma unroll
            for (int t = 0; t < 9; ++t) {
                short8 f;
#pragma unroll
                for (int j = 0; j < 8; ++j) {
                    int ci = kc * 32 + kq * 8 + j;
                    float wv = (ci < CIN) ? w[(co * CIN + ci) * 9 + t] : 0.f;
                    f[j] = f2bf(wv);
                }
                B[nt][kc][t] = f;
            }
    }
#pragma unroll 1
    for (int i = 0; i < 8; ++i) {
        int mt = wave * 8 + i;
        int y = mt >> 1, xh = (mt & 1) << 4;
        int x = xh + col;
        f32x4 acc[NT2];
#pragma unroll
        for (int nt = 0; nt < NT2; ++nt) acc[nt] = f32x4{bv[nt], bv[nt], bv[nt], bv[nt]};
#pragma unroll
        for (int dy = 0; dy < 3; ++dy) {
            int yp = y + dy - 1;
            if (yp < 0 || yp > 31) continue;  // wave-uniform
#pragma unroll
            for (int dx = 0; dx < 3; ++dx) {
                int xs = x + dx - 1;
                bool xv = (unsigned)xs < 32u;
                int xc = xs < 0 ? 0 : (xs > 31 ? 31 : xs);
                int rowbase = (yp * 32 + xc) * CS + kq * 8;
#pragma unroll
                for (int kc = 0; kc < KC; ++kc) {
                    short8 a = *(const short8*)(lds + rowbase + kc * 32);
                    if (!xv) a = short8{0, 0, 0, 0, 0, 0, 0, 0};
#pragma unroll
                    for (int nt = 0; nt < NT2; ++nt)
                        acc[nt] = __builtin_amdgcn_mfma_f32_16x16x32_bf16(
                            a, B[nt][kc][dy * 3 + dx], acc[nt], 0, 0, 0);
                }
            }
        }
        int prow = mt * 16 + kq * 4;
#pragma unroll
        for (int nt = 0; nt < NT2; ++nt) {
            int co = (ntbase + nt) * 16 + col;
#pragma unroll
            for (int r = 0; r < 4; ++r) {
                float v = acc[nt][r];
                if (RELU) v = fmaxf(v, 0.f);
                outb[(prow + r) * GOUT + co] = __float2bfloat16(v);
            }
        }
    }
}

// 3x3 zero-pad conv on one 32x32 block, bf16 MFMA. grid = n blocks, 512 threads.
template <int CIN, int COUT, bool RELU, bool WANTC>
__global__ __launch_bounds__(512, 2) void k_bconv(const __hip_bfloat16* __restrict__ in,
                                                  const float* __restrict__ w,
                                                  const float* __restrict__ bias,
                                                  const float* __restrict__ clsv, int b0,
                                                  __hip_bfloat16* __restrict__ out) {
    constexpr int KC = (CIN + 31) / 32;
    constexpr int CS = (CIN == 64) ? 72 : 40;   // padded LDS row stride (16B-aligned rows)
    constexpr int GIN = 64;
    constexpr int GOUT = (COUT == 48) ? 48 : 64;
    extern __shared__ unsigned short sh[];
    int bL = blockIdx.x;
    if ((clsv[b0 + bL] > 0.5f) != WANTC) return;
    int tid = threadIdx.x;
    const unsigned short* inb = (const unsigned short*)in + (long)bL * (1024 * GIN);
    constexpr int UPR = CIN / 8;  // ushort8 units per row
    for (int u = tid; u < 1024 * UPR; u += 512) {
        int p = u / UPR, cq = u % UPR;
        ushort8 v = *(const ushort8*)(inb + p * GIN + cq * 8);
        *(ushort8*)(sh + p * CS + cq * 8) = v;
    }
    if (CIN == 16) {
        ushort8 z = {0, 0, 0, 0, 0, 0, 0, 0};
        for (int u = tid; u < 2048; u += 512) {
            int p = u >> 1, cq = u & 1;
            *(ushort8*)(sh + p * CS + 16 + cq * 8) = z;
        }
    }
    __syncthreads();
    __hip_bfloat16* outb = out + (long)bL * (1024 * GOUT);
    if (COUT == 64) {
        bconv_pass<2, KC, CIN, CS, GOUT, RELU>(sh, w, bias, 0, tid, outb);
        bconv_pass<2, KC, CIN, CS, GOUT, RELU>(sh, w, bias, 2, tid, outb);
    } else if (COUT == 48) {
        bconv_pass<2, KC, CIN, CS, GOUT, RELU>(sh, w, bias, 0, tid, outb);
        bconv_pass<1, KC, CIN, CS, GOUT, RELU>(sh, w, bias, 2, tid, outb);
    } else {
        bconv_pass<1, KC, CIN, CS, GOUT, RELU>(sh, w, bias, 0, tid, outb);
    }
}

// pixel shuffle + clip + crop + reassemble from bf16 t3 [p][48]
__global__ __launch_bounds__(256) void k_assemble(const unsigned short* __restrict__ t3,
                                                  int b0, int nb, float* __restrict__ out) {
    int idx = blockIdx.x * 256 + threadIdx.x;
    if (idx >= nb * 19200) return;
    int bL = idx / 19200;
    int rem = idx - bL * 19200;
    int ch = rem / 6400;
    int rem2 = rem - ch * 6400;
    int r = rem2 / 80, s = rem2 - r * 80;
    int b = b0 + bL;
    int bh = b / NW, bw = b - bh * NW;
    int yy = r + 24, xx = s + 24;
    int pc = ch * 16 + (yy & 3) * 4 + (xx & 3);
    float v = bf2f(t3[(long)bL * 49152 + ((yy >> 2) * 32 + (xx >> 2)) * 48 + pc]);
    v = fminf(fmaxf(v, 0.f), 1.f);
    out[ch * (1920 * 1280) + (bh * 80 + r) * 1280 + (bw * 80 + s)] = v;
}

extern "C" void kernel_launch(void* const* d_in, const int* in_sizes, int n_in,
                              void* d_out, int out_size, void* d_ws, size_t ws_size,
                              hipStream_t stream) {
    const float* x      = (const float*)d_in[0];
    const float* cls_w1 = (const float*)d_in[1];
    const float* cls_b1 = (const float*)d_in[2];
    const float* cls_w2 = (const float*)d_in[3];
    const float* cls_b2 = (const float*)d_in[4];
    const float* cls_w3 = (const float*)d_in[5];
    const float* cls_b3 = (const float*)d_in[6];
    const float* cls_w4 = (const float*)d_in[7];
    const float* cls_b4 = (const float*)d_in[8];
    const float* cls_w5 = (const float*)d_in[9];
    const float* cls_b5 = (const float*)d_in[10];
    const float* lt_w1  = (const float*)d_in[11];
    const float* lt_b1  = (const float*)d_in[12];
    const float* lt_w2  = (const float*)d_in[13];
    const float* lt_b2  = (const float*)d_in[14];
    const float* cx_w1  = (const float*)d_in[15];
    const float* cx_b1  = (const float*)d_in[16];
    const float* cx_w2  = (const float*)d_in[17];
    const float* cx_b2  = (const float*)d_in[18];
    const float* cx_w3  = (const float*)d_in[19];
    const float* cx_b3  = (const float*)d_in[20];

    float* ws = (float*)d_ws;
    float* out = (float*)d_out;

    size_t off = 0;
    float* c1 = ws + off;  off += (size_t)32 * HW;
    float* c2 = ws + off;  off += (size_t)32 * HW2;
    float* c3 = ws + off;  off += (size_t)16 * HW2;
    float* c4 = ws + off;  off += (size_t)8 * HW4;
    float* clsv = ws + off; off += 384;
    size_t fixed = off;  // floats; 16B-aligned

    // bf16 per-block temporaries: t1[1024][64], t2[1024][64], t3[1024][48]
    long avail_bytes = (long)ws_size - (long)fixed * 4;
    long per_block_bytes = (65536 + 65536 + 49152) * 2;  // 360448
    long cmax = avail_bytes / per_block_bytes;
    int chunk = (int)(cmax < 1 ? 1 : (cmax > NB ? NB : cmax));
    __hip_bfloat16* t1 = (__hip_bfloat16*)(ws + fixed);
    __hip_bfloat16* t2 = t1 + (long)chunk * 65536;
    __hip_bfloat16* t3 = t2 + (long)chunk * 65536;

    // raise dynamic-LDS caps (idempotent host-side calls; not stream ops)
    (void)hipFuncSetAttribute((const void*)k_first,
                              hipFuncAttributeMaxDynamicSharedMemorySize, 88856);
    (void)hipFuncSetAttribute((const void*)(k_bconv<64, 64, true, true>),
                              hipFuncAttributeMaxDynamicSharedMemorySize, 147456);
    (void)hipFuncSetAttribute((const void*)(k_bconv<64, 48, false, true>),
                              hipFuncAttributeMaxDynamicSharedMemorySize, 147456);
    (void)hipFuncSetAttribute((const void*)(k_bconv<16, 48, false, false>),
                              hipFuncAttributeMaxDynamicSharedMemorySize, 81920);

    k_cls1<<<(HW + 255) / 256, 256, 0, stream>>>(x, cls_w1, cls_b1, c1);
    k_cls2<<<dim3((HW2 + 255) / 256, 4), 256, 0, stream>>>(c1, cls_w2, cls_b2, c2);
    k_cls3<<<(HW2 + 255) / 256, 256, 0, stream>>>(c2, cls_w3, cls_b3, c3);
    k_cls4<<<(HW4 + 255) / 256, 256, 0, stream>>>(c3, cls_w4, cls_b4, c4);
    k_cls5<<<1, 384, 0, stream>>>(c4, cls_w5, cls_b5, clsv, out + IMG_PIX);

    for (int b0 = 0; b0 < NB; b0 += chunk) {
        int n = chunk < (NB - b0) ? chunk : (NB - b0);
        k_first<<<n, 512, 88856, stream>>>(x, lt_w1, lt_b1, cx_w1, cx_b1, clsv, b0, t1);
        k_bconv<64, 64, true, true><<<n, 512, 147456, stream>>>(t1, cx_w2, cx_b2, clsv, b0, t2);
        k_bconv<64, 48, false, true><<<n, 512, 147456, stream>>>(t2, cx_w3, cx_b3, clsv, b0, t3);
        k_bconv<16, 48, false, false><<<n, 512, 81920, stream>>>(t1, lt_w2, lt_b2, clsv, b0, t3);
        k_assemble<<<(n * 19200 + 255) / 256, 256, 0, stream>>>(
            (const unsigned short*)t3, b0, n, out);
    }
}

// Round 3
// 304.912 us; speedup vs baseline: 14.8819x; 1.4482x over previous
//
#include <hip/hip_runtime.h>
#include <hip/hip_bf16.h>
#include <math.h>

static constexpr int H = 480, W = 320, NH = 24, NW = 16, NB = 384;
static constexpr int HW = H * W;            // 153600
static constexpr int H2 = 240, W2 = 160;
static constexpr int HW2 = H2 * W2;         // 38400
static constexpr int H4 = 120, W4 = 80;
static constexpr int HW4 = H4 * W4;         // 9600
static constexpr int IMG_PIX = 3 * 1920 * 1280;  // 7372800

typedef __attribute__((ext_vector_type(8))) short short8;
typedef __attribute__((ext_vector_type(4))) float f32x4;
typedef __attribute__((ext_vector_type(8))) unsigned short ushort8;

// packed-weight region offsets (ushort elements)
static constexpr int WPK_CX2 = 0;          // [64][9][64]
static constexpr int WPK_CX3 = 36864;      // [48][9][64]
static constexpr int WPK_LT2 = 64512;      // [48][9][32] (ci>=16 zero)
static constexpr int WPK_F_CX = 78336;     // [64][32] (k>=27 zero)
static constexpr int WPK_F_LT = 80384;     // [16][32]
static constexpr int WPK_TOT = 80896;

__device__ __forceinline__ int iclamp(int v, int lo, int hi) {
    return v < lo ? lo : (v > hi ? hi : v);
}
__device__ __forceinline__ unsigned short f2bfu(float x) {
    __hip_bfloat16 h = __float2bfloat16(x);
    return *reinterpret_cast<unsigned short*>(&h);
}
__device__ __forceinline__ float bf2f(unsigned short u) {
    __hip_bfloat16 h = *reinterpret_cast<__hip_bfloat16*>(&u);
    return __bfloat162float(h);
}

// ---------------- weight pre-pack ----------------

__global__ __launch_bounds__(256) void k_pack(const float* __restrict__ cx_w2,
                                              const float* __restrict__ cx_w3,
                                              const float* __restrict__ lt_w2,
                                              const float* __restrict__ cx_w1,
                                              const float* __restrict__ lt_w1,
                                              unsigned short* __restrict__ wpk) {
    int i = blockIdx.x * 256 + threadIdx.x;
    if (i >= WPK_TOT) return;
    float v = 0.f;
    if (i < WPK_CX3) {
        int co = i / 576, t = (i / 64) % 9, ci = i % 64;
        v = cx_w2[(co * 64 + ci) * 9 + t];
    } else if (i < WPK_LT2) {
        int j = i - WPK_CX3;
        int co = j / 576, t = (j / 64) % 9, ci = j % 64;
        v = cx_w3[(co * 64 + ci) * 9 + t];
    } else if (i < WPK_F_CX) {
        int j = i - WPK_LT2;
        int co = j / 288, t = (j / 32) % 9, ci = j % 32;
        v = (ci < 16) ? lt_w2[(co * 16 + ci) * 9 + t] : 0.f;
    } else if (i < WPK_F_LT) {
        int j = i - WPK_F_CX;
        int co = j >> 5, k = j & 31;
        v = (k < 27) ? cx_w1[co * 27 + k] : 0.f;
    } else {
        int j = i - WPK_F_LT;
        int co = j >> 5, k = j & 31;
        v = (k < 27) ? lt_w1[co * 27 + k] : 0.f;
    }
    wpk[i] = f2bfu(v);
}

// ---------------- classifier (fp32, unchanged) ----------------

__global__ __launch_bounds__(256) void k_cls1(const float* __restrict__ x,
                                              const float* __restrict__ w,
                                              const float* __restrict__ b,
                                              float* __restrict__ out) {
    int p = blockIdx.x * 256 + threadIdx.x;
    if (p >= HW) return;
    int y = p / W, xx = p - y * W;
    float in[3][9];
#pragma unroll
    for (int ci = 0; ci < 3; ++ci)
#pragma unroll
        for (int dy = 0; dy < 3; ++dy) {
            int yy = iclamp(y + dy - 1, 0, H - 1);
#pragma unroll
            for (int dx = 0; dx < 3; ++dx) {
                int xc = iclamp(xx + dx - 1, 0, W - 1);
                in[ci][dy * 3 + dx] = x[ci * HW + yy * W + xc];
            }
        }
#pragma unroll
    for (int co = 0; co < 32; ++co) {
        float acc = b[co];
#pragma unroll
        for (int k = 0; k < 27; ++k) acc = fmaf(w[co * 27 + k], in[k / 9][k % 9], acc);
        out[co * HW + p] = fmaxf(acc, 0.f);
    }
}

__global__ __launch_bounds__(256) void k_cls2(const float* __restrict__ in,
                                              const float* __restrict__ w,
                                              const float* __restrict__ b,
                                              float* __restrict__ out) {
    int p = blockIdx.x * 256 + threadIdx.x;
    if (p >= HW2) return;
    int py = p / W2, px = p - py * W2;
    int coc = blockIdx.y;
    float acc[8][4];
#pragma unroll
    for (int co = 0; co < 8; ++co) {
        float bb = b[coc * 8 + co];
        acc[co][0] = bb; acc[co][1] = bb; acc[co][2] = bb; acc[co][3] = bb;
    }
    for (int ci = 0; ci < 32; ++ci) {
        float v[4][4];
#pragma unroll
        for (int i = 0; i < 4; ++i) {
            int yr = iclamp(2 * py - 1 + i, 0, H - 1);
#pragma unroll
            for (int j = 0; j < 4; ++j) {
                int xc = iclamp(2 * px - 1 + j, 0, W - 1);
                v[i][j] = in[ci * HW + yr * W + xc];
            }
        }
#pragma unroll
        for (int co = 0; co < 8; ++co) {
            const float* wp = w + (coc * 8 + co) * 288 + ci * 9;
#pragma unroll
            for (int dy = 0; dy < 3; ++dy)
#pragma unroll
                for (int dx = 0; dx < 3; ++dx) {
                    float ww = wp[dy * 3 + dx];
                    acc[co][0] = fmaf(ww, v[dy][dx], acc[co][0]);
                    acc[co][1] = fmaf(ww, v[dy][dx + 1], acc[co][1]);
                    acc[co][2] = fmaf(ww, v[dy + 1][dx], acc[co][2]);
                    acc[co][3] = fmaf(ww, v[dy + 1][dx + 1], acc[co][3]);
                }
        }
    }
#pragma unroll
    for (int co = 0; co < 8; ++co) {
        float m = fmaxf(fmaxf(acc[co][0], acc[co][1]), fmaxf(acc[co][2], acc[co][3]));
        out[(coc * 8 + co) * HW2 + p] = fmaxf(m, 0.f);
    }
}

__global__ __launch_bounds__(256) void k_cls3(const float* __restrict__ in,
                                              const float* __restrict__ w,
                                              const float* __restrict__ b,
                                              float* __restrict__ out) {
    int p = blockIdx.x * 256 + threadIdx.x;
    if (p >= HW2) return;
    int y = p / W2, xx = p - y * W2;
    float acc[16];
#pragma unroll
    for (int co = 0; co < 16; ++co) acc[co] = b[co];
    for (int ci = 0; ci < 32; ++ci) {
        float v[9];
#pragma unroll
        for (int dy = 0; dy < 3; ++dy) {
            int yy = iclamp(y + dy - 1, 0, H2 - 1);
#pragma unroll
            for (int dx = 0; dx < 3; ++dx) {
                int xc = iclamp(xx + dx - 1, 0, W2 - 1);
                v[dy * 3 + dx] = in[ci * HW2 + yy * W2 + xc];
            }
        }
#pragma unroll
        for (int co = 0; co < 16; ++co)
#pragma unroll
            for (int t = 0; t < 9; ++t)
                acc[co] = fmaf(w[co * 288 + ci * 9 + t], v[t], acc[co]);
    }
#pragma unroll
    for (int co = 0; co < 16; ++co) out[co * HW2 + p] = fmaxf(acc[co], 0.f);
}

__global__ __launch_bounds__(256) void k_cls4(const float* __restrict__ in,
                                              const float* __restrict__ w,
                                              const float* __restrict__ b,
                                              float* __restrict__ out) {
    int p = blockIdx.x * 256 + threadIdx.x;
    if (p >= HW4) return;
    int py = p / W4, px = p - py * W4;
    float acc[8][4];
#pragma unroll
    for (int co = 0; co < 8; ++co) {
        float bb = b[co];
        acc[co][0] = bb; acc[co][1] = bb; acc[co][2] = bb; acc[co][3] = bb;
    }
    for (int ci = 0; ci < 16; ++ci) {
        float v[4][4];
#pragma unroll
        for (int i = 0; i < 4; ++i) {
            int yr = iclamp(2 * py - 1 + i, 0, H2 - 1);
#pragma unroll
            for (int j = 0; j < 4; ++j) {
                int xc = iclamp(2 * px - 1 + j, 0, W2 - 1);
                v[i][j] = in[ci * HW2 + yr * W2 + xc];
            }
        }
#pragma unroll
        for (int co = 0; co < 8; ++co) {
            const float* wp = w + co * 144 + ci * 9;
#pragma unroll
            for (int dy = 0; dy < 3; ++dy)
#pragma unroll
                for (int dx = 0; dx < 3; ++dx) {
                    float ww = wp[dy * 3 + dx];
                    acc[co][0] = fmaf(ww, v[dy][dx], acc[co][0]);
                    acc[co][1] = fmaf(ww, v[dy][dx + 1], acc[co][1]);
                    acc[co][2] = fmaf(ww, v[dy + 1][dx], acc[co][2]);
                    acc[co][3] = fmaf(ww, v[dy + 1][dx + 1], acc[co][3]);
                }
        }
    }
#pragma unroll
    for (int co = 0; co < 8; ++co) {
        float m = fmaxf(fmaxf(acc[co][0], acc[co][1]), fmaxf(acc[co][2], acc[co][3]));
        out[co * HW4 + p] = fmaxf(m, 0.f);
    }
}

__global__ __launch_bounds__(384) void k_cls5(const float* __restrict__ in,
                                              const float* __restrict__ w,
                                              const float* __restrict__ b,
                                              float* __restrict__ clsv,
                                              float* __restrict__ out_cls) {
    int tid = threadIdx.x;
    if (tid >= NB) return;
    int oy = tid / NW, ox = tid - oy * NW;
    float s = b[0];
    for (int ci = 0; ci < 8; ++ci)
#pragma unroll
        for (int ky = 0; ky < 5; ++ky)
#pragma unroll
            for (int kx = 0; kx < 5; ++kx)
                s = fmaf(w[ci * 25 + ky * 5 + kx],
                         in[ci * HW4 + (oy * 5 + ky) * W4 + (ox * 5 + kx)], s);
    float sig = 1.f / (1.f + expf(-s));
    clsv[tid] = sig;
    out_cls[tid] = sig;
}

// ---------------- block branches: bf16 MFMA ----------------

// first conv of both branches via im2col + MFMA. grid = n blocks, 512 threads.
__global__ __launch_bounds__(512) void k_first(const float* __restrict__ x,
                                               const unsigned short* __restrict__ wpk,
                                               const float* __restrict__ bl,
                                               const float* __restrict__ bc,
                                               const float* __restrict__ clsv,
                                               int b0, __hip_bfloat16* __restrict__ t1) {
    extern __shared__ unsigned short sh[];
    unsigned short* A = sh;                 // 1024*40
    unsigned short* halo = sh + 1024 * 40;  // 3*1156
    int bL = blockIdx.x, b = b0 + bL;
    bool cx = clsv[b] > 0.5f;
    int bh = b / NW, bw = b - bh * NW;
    int tid = threadIdx.x;
    for (int i = tid; i < 3 * 1156; i += 512) {
        int ci = i / 1156, rem = i - ci * 1156;
        int ry = rem / 34, rx = rem - ry * 34;
        int yg = bh * 20 + ry - 7, xg = bw * 20 + rx - 7;
        float v = ((unsigned)yg < (unsigned)H && (unsigned)xg < (unsigned)W)
                      ? x[ci * HW + yg * W + xg] : 0.f;
        halo[i] = f2bfu(v);
    }
    __syncthreads();
    for (int v = tid; v < 1024 * 32; v += 512) {
        int p = v >> 5, k = v & 31;
        unsigned short val = 0;
        if (k < 27) {
            int ci = k / 9, t = k - ci * 9;
            int dy = t / 3, dx = t - dy * 3;
            int y = p >> 5, xx = p & 31;
            val = halo[ci * 1156 + (y + dy) * 34 + (xx + dx)];
        }
        A[p * 40 + k] = val;
    }
    __syncthreads();
    int lane = tid & 63, wave = tid >> 6;
    int col = lane & 15, kq = lane >> 4;
    const unsigned short* wf = wpk + (cx ? WPK_F_CX : WPK_F_LT);
    const float* bi = cx ? bc : bl;
    int nT = cx ? 4 : 1;
    __hip_bfloat16* outb = t1 + (long)bL * 65536;
    for (int nt = 0; nt < nT; ++nt) {
        int co = nt * 16 + col;
        short8 Bf = *(const short8*)(wf + co * 32 + kq * 8);
        float bv = bi[co];
#pragma unroll 1
        for (int i = 0; i < 8; ++i) {
            int mt = wave * 8 + i;
            short8 a = *(const short8*)(A + (mt * 16 + col) * 40 + kq * 8);
            f32x4 acc = {bv, bv, bv, bv};
            acc = __builtin_amdgcn_mfma_f32_16x16x32_bf16(a, Bf, acc, 0, 0, 0);
            int prow = mt * 16 + kq * 4;
#pragma unroll
            for (int r = 0; r < 4; ++r)
                outb[(prow + r) * 64 + co] = __float2bfloat16(fmaxf(acc[r], 0.f));
        }
    }
}

// taps-outer conv over one 32x32 block from XOR-swizzled LDS.
// CINP in {32,64} (LDS row stride, shorts); NT = COUT/16; GOUT = out row stride.
template <int CINP, int NT, int GOUT, bool RELU>
__device__ __forceinline__ void conv_mfma(const unsigned short* __restrict__ sh,
                                          const unsigned short* __restrict__ wpk,
                                          const float* __restrict__ bias,
                                          unsigned short* __restrict__ outg, int tid) {
    constexpr int KC = CINP / 32;
    int lane = tid & 63, wave = tid >> 6;
    int col = lane & 15, kq = lane >> 4;
    f32x4 acc[8][NT];
#pragma unroll
    for (int nt = 0; nt < NT; ++nt) {
        float bv = bias[nt * 16 + col];
#pragma unroll
        for (int i = 0; i < 8; ++i) acc[i][nt] = f32x4{bv, bv, bv, bv};
    }
#pragma unroll 1
    for (int t = 0; t < 9; ++t) {
        int dy = t / 3, dx = t - dy * 3;
        short8 B[NT][KC];
#pragma unroll
        for (int nt = 0; nt < NT; ++nt)
#pragma unroll
            for (int kc = 0; kc < KC; ++kc)
                B[nt][kc] = *(const short8*)(wpk + ((nt * 16 + col) * 9 + t) * CINP +
                                             kc * 32 + kq * 8);
#pragma unroll
        for (int i = 0; i < 8; ++i) {
            int mt = wave * 8 + i;
            int yp = (mt >> 1) + dy - 1;
            if ((unsigned)yp > 31u) continue;  // wave-uniform skip
            int xs = ((mt & 1) << 4) + col + dx - 1;
            bool xv = (unsigned)xs < 32u;
            int xc = xs < 0 ? 0 : (xs > 31 ? 31 : xs);
            int pr = yp * 32 + xc;
#pragma unroll
            for (int kc = 0; kc < KC; ++kc) {
                int c = kc * 4 + kq;
                int cs = (CINP == 64) ? (c ^ (pr & 7)) : (c ^ ((pr >> 1) & 3));
                short8 a = *(const short8*)(sh + pr * CINP + cs * 8);
                if (!xv) a = short8{0, 0, 0, 0, 0, 0, 0, 0};
#pragma unroll
                for (int nt = 0; nt < NT; ++nt)
                    acc[i][nt] = __builtin_amdgcn_mfma_f32_16x16x32_bf16(a, B[nt][kc],
                                                                         acc[i][nt], 0, 0, 0);
            }
        }
    }
#pragma unroll
    for (int i = 0; i < 8; ++i) {
        int prow = (wave * 8 + i) * 16 + kq * 4;
#pragma unroll
        for (int nt = 0; nt < NT; ++nt) {
            int co = nt * 16 + col;
#pragma unroll
            for (int r = 0; r < 4; ++r) {
                float v = acc[i][nt][r];
                if (RELU) v = fmaxf(v, 0.f);
                outg[(prow + r) * GOUT + co] = f2bfu(v);
            }
        }
    }
}

// merged second conv: cx blocks do 64->64 (t1->t2, relu); lt blocks do 16->48 (t1->t3).
__global__ __launch_bounds__(512) void k_b2(const __hip_bfloat16* __restrict__ t1,
                                            const unsigned short* __restrict__ wpk,
                                            const float* __restrict__ cx_b2,
                                            const float* __restrict__ lt_b2,
                                            const float* __restrict__ clsv, int b0,
                                            __hip_bfloat16* __restrict__ t2,
                                            __hip_bfloat16* __restrict__ t3) {
    extern __shared__ unsigned short sh[];
    int bL = blockIdx.x;
    bool cx = clsv[b0 + bL] > 0.5f;
    int tid = threadIdx.x;
    const unsigned short* inb = (const unsigned short*)t1 + (long)bL * 65536;
    if (cx) {
        for (int u = tid; u < 8192; u += 512) {
            int p = u >> 3, c = u & 7;
            *(ushort8*)(sh + p * 64 + (c ^ (p & 7)) * 8) =
                *(const ushort8*)(inb + p * 64 + c * 8);
        }
        __syncthreads();
        conv_mfma<64, 4, 64, true>(sh, wpk + WPK_CX2, cx_b2,
                                   (unsigned short*)t2 + (long)bL * 65536, tid);
    } else {
        ushort8 z = {0, 0, 0, 0, 0, 0, 0, 0};
        for (int u = tid; u < 4096; u += 512) {
            int p = u >> 2, c = u & 3;
            ushort8 v = (c < 2) ? *(const ushort8*)(inb + p * 64 + c * 8) : z;
            *(ushort8*)(sh + p * 32 + (c ^ ((p >> 1) & 3)) * 8) = v;
        }
        __syncthreads();
        conv_mfma<32, 3, 48, false>(sh, wpk + WPK_LT2, lt_b2,
                                    (unsigned short*)t3 + (long)bL * 49152, tid);
    }
}

// third conv, cx only: 64->48 (t2->t3).
__global__ __launch_bounds__(512) void k_b3(const __hip_bfloat16* __restrict__ t2,
                                            const unsigned short* __restrict__ wpk,
                                            const float* __restrict__ cx_b3,
                                            const float* __restrict__ clsv, int b0,
                                            __hip_bfloat16* __restrict__ t3) {
    extern __shared__ unsigned short sh[];
    int bL = blockIdx.x;
    if (!(clsv[b0 + bL] > 0.5f)) return;
    int tid = threadIdx.x;
    const unsigned short* inb = (const unsigned short*)t2 + (long)bL * 65536;
    for (int u = tid; u < 8192; u += 512) {
        int p = u >> 3, c = u & 7;
        *(ushort8*)(sh + p * 64 + (c ^ (p & 7)) * 8) = *(const ushort8*)(inb + p * 64 + c * 8);
    }
    __syncthreads();
    conv_mfma<64, 3, 48, false>(sh, wpk + WPK_CX3, cx_b3,
                                (unsigned short*)t3 + (long)bL * 49152, tid);
}

// pixel shuffle + clip + crop + reassemble from bf16 t3 [p][48]
__global__ __launch_bounds__(256) void k_assemble(const unsigned short* __restrict__ t3,
                                                  int b0, int nb, float* __restrict__ out) {
    int idx = blockIdx.x * 256 + threadIdx.x;
    if (idx >= nb * 19200) return;
    int bL = idx / 19200;
    int rem = idx - bL * 19200;
    int ch = rem / 6400;
    int rem2 = rem - ch * 6400;
    int r = rem2 / 80, s = rem2 - r * 80;
    int b = b0 + bL;
    int bh = b / NW, bw = b - bh * NW;
    int yy = r + 24, xx = s + 24;
    int pc = ch * 16 + (yy & 3) * 4 + (xx & 3);
    float v = bf2f(t3[(long)bL * 49152 + ((yy >> 2) * 32 + (xx >> 2)) * 48 + pc]);
    v = fminf(fmaxf(v, 0.f), 1.f);
    out[ch * (1920 * 1280) + (bh * 80 + r) * 1280 + (bw * 80 + s)] = v;
}

extern "C" void kernel_launch(void* const* d_in, const int* in_sizes, int n_in,
                              void* d_out, int out_size, void* d_ws, size_t ws_size,
                              hipStream_t stream) {
    const float* x      = (const float*)d_in[0];
    const float* cls_w1 = (const float*)d_in[1];
    const float* cls_b1 = (const float*)d_in[2];
    const float* cls_w2 = (const float*)d_in[3];
    const float* cls_b2 = (const float*)d_in[4];
    const float* cls_w3 = (const float*)d_in[5];
    const float* cls_b3 = (const float*)d_in[6];
    const float* cls_w4 = (const float*)d_in[7];
    const float* cls_b4 = (const float*)d_in[8];
    const float* cls_w5 = (const float*)d_in[9];
    const float* cls_b5 = (const float*)d_in[10];
    const float* lt_w1  = (const float*)d_in[11];
    const float* lt_b1  = (const float*)d_in[12];
    const float* lt_w2  = (const float*)d_in[13];
    const float* lt_b2  = (const float*)d_in[14];
    const float* cx_w1  = (const float*)d_in[15];
    const float* cx_b1  = (const float*)d_in[16];
    const float* cx_w2  = (const float*)d_in[17];
    const float* cx_b2  = (const float*)d_in[18];
    const float* cx_w3  = (const float*)d_in[19];
    const float* cx_b3  = (const float*)d_in[20];

    float* ws = (float*)d_ws;
    float* out = (float*)d_out;

    size_t off = 0;
    float* c1 = ws + off;  off += (size_t)32 * HW;
    float* c2 = ws + off;  off += (size_t)32 * HW2;
    float* c3 = ws + off;  off += (size_t)16 * HW2;
    float* c4 = ws + off;  off += (size_t)8 * HW4;
    float* clsv = ws + off; off += 384;
    unsigned short* wpk = (unsigned short*)(ws + off); off += (WPK_TOT + 1) / 2;
    size_t fixed = off;

    long avail_bytes = (long)ws_size - (long)fixed * 4;
    long per_block_bytes = (65536 + 65536 + 49152) * 2;  // 360448
    long cmax = avail_bytes / per_block_bytes;
    int chunk = (int)(cmax < 1 ? 1 : (cmax > NB ? NB : cmax));
    __hip_bfloat16* t1 = (__hip_bfloat16*)(ws + fixed);
    __hip_bfloat16* t2 = t1 + (long)chunk * 65536;
    __hip_bfloat16* t3 = t2 + (long)chunk * 65536;

    (void)hipFuncSetAttribute((const void*)k_first,
                              hipFuncAttributeMaxDynamicSharedMemorySize, 88856);
    (void)hipFuncSetAttribute((const void*)k_b2,
                              hipFuncAttributeMaxDynamicSharedMemorySize, 131072);
    (void)hipFuncSetAttribute((const void*)k_b3,
                              hipFuncAttributeMaxDynamicSharedMemorySize, 131072);

    k_pack<<<(WPK_TOT + 255) / 256, 256, 0, stream>>>(cx_w2, cx_w3, lt_w2, cx_w1, lt_w1, wpk);
    k_cls1<<<(HW + 255) / 256, 256, 0, stream>>>(x, cls_w1, cls_b1, c1);
    k_cls2<<<dim3((HW2 + 255) / 256, 4), 256, 0, stream>>>(c1, cls_w2, cls_b2, c2);
    k_cls3<<<(HW2 + 255) / 256, 256, 0, stream>>>(c2, cls_w3, cls_b3, c3);
    k_cls4<<<(HW4 + 255) / 256, 256, 0, stream>>>(c3, cls_w4, cls_b4, c4);
    k_cls5<<<1, 384, 0, stream>>>(c4, cls_w5, cls_b5, clsv, out + IMG_PIX);

    for (int b0 = 0; b0 < NB; b0 += chunk) {
        int n = chunk < (NB - b0) ? chunk : (NB - b0);
        k_first<<<n, 512, 88856, stream>>>(x, wpk, lt_b1, cx_b1, clsv, b0, t1);
        k_b2<<<n, 512, 131072, stream>>>(t1, wpk, cx_b2, lt_b2, clsv, b0, t2, t3);
        k_b3<<<n, 512, 131072, stream>>>(t2, wpk, cx_b3, clsv, b0, t3);
        k_assemble<<<(n * 19200 + 255) / 256, 256, 0, stream>>>(
            (const unsigned short*)t3, b0, n, out);
    }
}